// Round 2
// baseline (585.899 us; speedup 1.0000x reference)
//
#include <hip/hip_runtime.h>
#include <hip/hip_bf16.h>

#define NN 50000
#define NE 800000
#define NT 2000000
#define CUT 6.0f

// d_ws layout (bytes):
//   [0, 12,800,000)              float4 dirlen[NE]   (dir.xyz, len)
//   [12,800,000, 16,000,000)     float  elen[NE]     (dense lengths for mask)
//   [16,000,000, 16,000,064)     int    counter + pad
//   [16,000,064, 24,000,064)     int    list[NT]     (surviving triplet ids)
#define WS_ELEN   12800000
#define WS_CNT    16000000
#define WS_LIST   16000064

typedef __attribute__((ext_vector_type(8))) short short8;
typedef __attribute__((ext_vector_type(4))) float f32x4;

__device__ __forceinline__ short bf16hw(float f) {
    __hip_bfloat16 h = __float2bfloat16(f);
    return *reinterpret_cast<short*>(&h);
}

__device__ __forceinline__ float softplus_f(float x) {
    float t = __expf(-fabsf(x));
    return fmaxf(x, 0.0f) + __logf(1.0f + t);
}

__device__ __forceinline__ short8 to_bf8(float4 u, float4 v) {
    short8 r;
    r[0] = bf16hw(u.x); r[1] = bf16hw(u.y); r[2] = bf16hw(u.z); r[3] = bf16hw(u.w);
    r[4] = bf16hw(v.x); r[5] = bf16hw(v.y); r[6] = bf16hw(v.z); r[7] = bf16hw(v.w);
    return r;
}

struct MlpW {
    short8 wb[2][2][4];   // [layer][ktile][ntile] B-frags, BN scale folded in
    float bias[2][4];     // fused linear-bias + BN shift (per lane's col)
    float wo[4];
    float bo;
};

__device__ __forceinline__ void load_weights(
    const float* __restrict__ W, const float* __restrict__ b,
    const float* __restrict__ g, const float* __restrict__ bt,
    const float* __restrict__ m, const float* __restrict__ v,
    const float* __restrict__ Wo, const float* __restrict__ bo, MlpW& w) {
    const int lane = threadIdx.x & 63;
    const int grp = lane >> 4, c = lane & 15;
#pragma unroll
    for (int l = 0; l < 2; ++l)
#pragma unroll
        for (int nt = 0; nt < 4; ++nt) {
            int j = nt * 16 + c;
            float s = g[l * 64 + j] * rsqrtf(v[l * 64 + j] + 1e-5f);
            w.bias[l][nt] = (b[l * 64 + j] - m[l * 64 + j]) * s + bt[l * 64 + j];
#pragma unroll
            for (int kt = 0; kt < 2; ++kt) {
                short8 f;
#pragma unroll
                for (int i = 0; i < 8; ++i)
                    f[i] = bf16hw(W[l * 4096 + (kt * 32 + grp * 8 + i) * 64 + j] * s);
                w.wb[l][kt][nt] = f;
            }
        }
#pragma unroll
    for (int nt = 0; nt < 4; ++nt) w.wo[nt] = Wo[nt * 16 + c];
    w.bo = bo[0];
}

// MLP on 16 rows (one wave). Lane's row for A-frags = lane&15, at float offset
// row_off (per-lane). out_s[r] = scalar for local row (lane>>4)*4 + r.
__device__ __forceinline__ void mlp_tile(const float* __restrict__ xbase, size_t row_off,
                                         const MlpW& w, unsigned short* lds, float out_s[4]) {
    const int lane = threadIdx.x & 63;
    const int grp = lane >> 4, c = lane & 15;
    const float4* rp = (const float4*)(xbase + row_off + grp * 8);
    float4 x0 = rp[0], x1 = rp[1], x2 = rp[8], x3 = rp[9];
    short8 a0 = to_bf8(x0, x1), a1 = to_bf8(x2, x3);
    f32x4 acc[4];
#pragma unroll
    for (int nt = 0; nt < 4; ++nt) {
        f32x4 z = {0.f, 0.f, 0.f, 0.f};
        z = __builtin_amdgcn_mfma_f32_16x16x32_bf16(a0, w.wb[0][0][nt], z, 0, 0, 0);
        z = __builtin_amdgcn_mfma_f32_16x16x32_bf16(a1, w.wb[0][1][nt], z, 0, 0, 0);
        acc[nt] = z;
    }
#pragma unroll
    for (int nt = 0; nt < 4; ++nt)
#pragma unroll
        for (int r = 0; r < 4; ++r) {
            float y = softplus_f(acc[nt][r] + w.bias[0][nt]);
            int row = grp * 4 + r;
            int byte = (row * 128 + (nt * 16 + c) * 2) ^ ((row & 7) << 4);
            *(unsigned short*)((char*)lds + byte) = (unsigned short)bf16hw(y);
        }
    asm volatile("s_waitcnt lgkmcnt(0)" ::: "memory");
    short8 b0 = *(const short8*)((char*)lds + ((c * 128 + grp * 16) ^ ((c & 7) << 4)));
    short8 b1 = *(const short8*)((char*)lds + ((c * 128 + 64 + grp * 16) ^ ((c & 7) << 4)));
    f32x4 acc2[4];
#pragma unroll
    for (int nt = 0; nt < 4; ++nt) {
        f32x4 z = {0.f, 0.f, 0.f, 0.f};
        z = __builtin_amdgcn_mfma_f32_16x16x32_bf16(b0, w.wb[1][0][nt], z, 0, 0, 0);
        z = __builtin_amdgcn_mfma_f32_16x16x32_bf16(b1, w.wb[1][1][nt], z, 0, 0, 0);
        acc2[nt] = z;
    }
    float p[4] = {0.f, 0.f, 0.f, 0.f};
#pragma unroll
    for (int nt = 0; nt < 4; ++nt)
#pragma unroll
        for (int r = 0; r < 4; ++r) {
            float y = softplus_f(acc2[nt][r] + w.bias[1][nt]);
            p[r] = fmaf(y, w.wo[nt], p[r]);
        }
#pragma unroll
    for (int msk = 1; msk < 16; msk <<= 1)
#pragma unroll
        for (int r = 0; r < 4; ++r) p[r] += __shfl_xor(p[r], msk);
#pragma unroll
    for (int r = 0; r < 4; ++r) out_s[r] = p[r] + w.bo;
}

// Dyad + scatter phase. sdata[el] = {dk.x,dk.y,dk.z, dj.x,dj.y,dj.z, s, tgt}
__device__ __forceinline__ void scatter_tile(const float (*sdata)[8], float* __restrict__ out) {
    const int lane = threadIdx.x & 63;
    asm volatile("s_waitcnt lgkmcnt(0)" ::: "memory");
#pragma unroll
    for (int p = 0; p < 3; ++p) {
        int idx = p * 64 + lane;
        if (idx < 144) {
            int el = idx / 9;
            int comp = idx - el * 9;
            int a = comp / 3, b2 = comp - a * 3;
            const float* sd = sdata[el];
            int tgt = __float_as_int(sd[7]);
            if (tgt >= 0) {
                float val = sd[6] * sd[a] * sd[3 + b2];
                atomicAdd(&out[tgt * 9 + comp], val);
            }
        }
    }
}

__global__ void geom_kernel(const float* __restrict__ pos,
                            const float* __restrict__ nbr_shift,
                            const int* __restrict__ edge_index,
                            float4* __restrict__ dirlen, float* __restrict__ elen) {
    int e = blockIdx.x * blockDim.x + threadIdx.x;
    if (e >= NE) return;
    int j = edge_index[e];
    int i = edge_index[NE + e];
    float dx = __fsub_rn(__fadd_rn(pos[i * 3 + 0], nbr_shift[e * 3 + 0]), pos[j * 3 + 0]);
    float dy = __fsub_rn(__fadd_rn(pos[i * 3 + 1], nbr_shift[e * 3 + 1]), pos[j * 3 + 1]);
    float dz = __fsub_rn(__fadd_rn(pos[i * 3 + 2], nbr_shift[e * 3 + 2]), pos[j * 3 + 2]);
    float l2 = __fadd_rn(__fadd_rn(__fmul_rn(dx, dx), __fmul_rn(dy, dy)), __fmul_rn(dz, dz));
    float len = __fsqrt_rn(l2);
    float4 o;
    o.x = __fdiv_rn(dx, len);
    o.y = __fdiv_rn(dy, len);
    o.z = __fdiv_rn(dz, len);
    o.w = len;
    dirlen[e] = o;
    elen[e] = len;
}

__global__ void compact_kernel(const int* __restrict__ idx_kj, const int* __restrict__ idx_ji,
                               const float* __restrict__ elen, int* __restrict__ counter,
                               int* __restrict__ list) {
    int t = blockIdx.x * blockDim.x + threadIdx.x;
    bool pass = false;
    if (t < NT)
        pass = (elen[idx_kj[t]] < CUT) && (elen[idx_ji[t]] < CUT);
    unsigned long long bal = __ballot(pass);
    int lane = threadIdx.x & 63;
    int base = 0;
    if (lane == 0) base = atomicAdd(counter, __popcll(bal));
    base = __shfl(base, 0);
    if (pass) list[base + __popcll(bal & ((1ull << lane) - 1ull))] = t;
}

__global__ __launch_bounds__(256) void edge_kernel(
    const float* __restrict__ edge_attr, const float* __restrict__ eW,
    const float* __restrict__ eb, const float* __restrict__ eg,
    const float* __restrict__ ebeta, const float* __restrict__ em,
    const float* __restrict__ ev, const float* __restrict__ eWo,
    const float* __restrict__ ebo, const int* __restrict__ edge_index,
    const float4* __restrict__ dirlen, float* __restrict__ out) {
    __shared__ __align__(16) unsigned short lds_t[4][1024];
    __shared__ __align__(16) float sdata[4][16][8];
    const int wave = threadIdx.x >> 6;
    const int lane = threadIdx.x & 63;
    MlpW w;
    load_weights(eW, eb, eg, ebeta, em, ev, eWo, ebo, w);
    const int gwave = blockIdx.x * 4 + wave;
    const int nwaves = gridDim.x * 4;
    const int ntiles = NE / 16;
    for (int tile = gwave; tile < ntiles; tile += nwaves) {
        float s[4];
        mlp_tile(edge_attr, (size_t)(tile * 16 + (lane & 15)) * 64, w, &lds_t[wave][0], s);
        if ((lane & 15) == 0) {
#pragma unroll
            for (int r = 0; r < 4; ++r) sdata[wave][(lane >> 4) * 4 + r][6] = s[r];
        }
        if (lane < 16) {
            int e = tile * 16 + lane;
            float4 d = dirlen[e];
            int tgt = edge_index[NE + e];
            float* sd = sdata[wave][lane];
            sd[0] = d.x; sd[1] = d.y; sd[2] = d.z;
            sd[3] = d.x; sd[4] = d.y; sd[5] = d.z;
            sd[7] = __int_as_float(tgt);
        }
        scatter_tile(sdata[wave], out);
    }
}

__global__ __launch_bounds__(256) void trip_kernel(
    const float* __restrict__ trip_attr, const float* __restrict__ tW,
    const float* __restrict__ tb, const float* __restrict__ tg,
    const float* __restrict__ tbeta, const float* __restrict__ tm,
    const float* __restrict__ tv, const float* __restrict__ tWo,
    const float* __restrict__ tbo, const int* __restrict__ idx_j,
    const int* __restrict__ idx_kj, const int* __restrict__ idx_ji,
    const float4* __restrict__ dirlen, const int* __restrict__ counter,
    const int* __restrict__ list, float* __restrict__ out) {
    __shared__ __align__(16) unsigned short lds_t[4][1024];
    __shared__ __align__(16) float sdata[4][16][8];
    const int wave = threadIdx.x >> 6;
    const int lane = threadIdx.x & 63;
    MlpW w;
    load_weights(tW, tb, tg, tbeta, tm, tv, tWo, tbo, w);
    const int cnt = *counter;
    const int gwave = blockIdx.x * 4 + wave;
    const int nwaves = gridDim.x * 4;
    const int ntiles = (cnt + 15) / 16;
    for (int tile = gwave; tile < ntiles; tile += nwaves) {
        int g = tile * 16 + (lane & 15);
        int trow = list[g < cnt ? g : 0];
        float s[4];
        mlp_tile(trip_attr, (size_t)trow * 64, w, &lds_t[wave][0], s);
        if ((lane & 15) == 0) {
#pragma unroll
            for (int r = 0; r < 4; ++r) sdata[wave][(lane >> 4) * 4 + r][6] = s[r];
        }
        if (lane < 16) {
            int gi = tile * 16 + lane;
            bool valid = gi < cnt;
            int t = list[valid ? gi : 0];
            int kj = idx_kj[t], ji = idx_ji[t];
            float4 dk = dirlen[kj];
            float4 dj = dirlen[ji];
            int tgt = valid ? idx_j[t] : -1;
            float* sd = sdata[wave][lane];
            sd[0] = dk.x; sd[1] = dk.y; sd[2] = dk.z;
            sd[3] = dj.x; sd[4] = dj.y; sd[5] = dj.z;
            sd[7] = __int_as_float(tgt);
        }
        scatter_tile(sdata[wave], out);
    }
}

extern "C" void kernel_launch(void* const* d_in, const int* in_sizes, int n_in,
                              void* d_out, int out_size, void* d_ws, size_t ws_size,
                              hipStream_t stream) {
    const float* pos       = (const float*)d_in[0];
    const float* nbr_shift = (const float*)d_in[1];
    const float* edge_attr = (const float*)d_in[2];
    const float* trip_attr = (const float*)d_in[3];
    const float* eW    = (const float*)d_in[4];
    const float* eb    = (const float*)d_in[5];
    const float* eg    = (const float*)d_in[6];
    const float* ebeta = (const float*)d_in[7];
    const float* em    = (const float*)d_in[8];
    const float* ev    = (const float*)d_in[9];
    const float* eWo   = (const float*)d_in[10];
    const float* ebo   = (const float*)d_in[11];
    const float* tW    = (const float*)d_in[12];
    const float* tb    = (const float*)d_in[13];
    const float* tg    = (const float*)d_in[14];
    const float* tbeta = (const float*)d_in[15];
    const float* tm    = (const float*)d_in[16];
    const float* tv    = (const float*)d_in[17];
    const float* tWo   = (const float*)d_in[18];
    const float* tbo   = (const float*)d_in[19];
    const int* edge_index = (const int*)d_in[20];
    const int* idx_j      = (const int*)d_in[21];
    const int* idx_kj     = (const int*)d_in[22];
    const int* idx_ji     = (const int*)d_in[23];
    float* out = (float*)d_out;

    char* ws = (char*)d_ws;
    float4* dirlen = (float4*)ws;
    float* elen    = (float*)(ws + WS_ELEN);
    int* counter   = (int*)(ws + WS_CNT);
    int* list      = (int*)(ws + WS_LIST);

    hipMemsetAsync(d_out, 0, (size_t)out_size * sizeof(float), stream);
    hipMemsetAsync(counter, 0, 64, stream);
    geom_kernel<<<(NE + 255) / 256, 256, 0, stream>>>(pos, nbr_shift, edge_index, dirlen, elen);
    compact_kernel<<<(NT + 255) / 256, 256, 0, stream>>>(idx_kj, idx_ji, elen, counter, list);
    edge_kernel<<<1024, 256, 0, stream>>>(edge_attr, eW, eb, eg, ebeta, em, ev, eWo, ebo,
                                          edge_index, dirlen, out);
    trip_kernel<<<1024, 256, 0, stream>>>(trip_attr, tW, tb, tg, tbeta, tm, tv, tWo, tbo,
                                          idx_j, idx_kj, idx_ji, dirlen, counter, list, out);
}

// Round 3
// 318.309 us; speedup vs baseline: 1.8407x; 1.8407x over previous
//
#include <hip/hip_runtime.h>
#include <hip/hip_bf16.h>

#define NN 50000
#define NE 800000
#define NT 2000000
#define CUT 6.0f

// compaction geometry: one wave (64 lanes) handles 2048 triplets
#define ITEMS_PER_WAVE 2048
#define NWAVES ((NT + ITEMS_PER_WAVE - 1) / ITEMS_PER_WAVE)   // 977

// d_ws layout (bytes):
//   [0, 12,800,000)           float4 dirlen[NE]  (dir.xyz, len)
//   [12,800,000, +64)         int counter
//   [12,800,064, +4032)       int waveCounts[NWAVES]
//   [12,804,096, +4096)       int waveOffsets[NWAVES]
//   [12,808,192, +8,000,000)  int list[NT]
#define WS_CNT    12800000
#define WS_WCNT   12800064
#define WS_WOFF   12804096
#define WS_LIST   12808192

typedef __attribute__((ext_vector_type(8))) short short8;
typedef __attribute__((ext_vector_type(4))) float f32x4;

__device__ __forceinline__ short bf16hw(float f) {
    __hip_bfloat16 h = __float2bfloat16(f);
    return *reinterpret_cast<short*>(&h);
}

__device__ __forceinline__ float softplus_f(float x) {
    float t = __expf(-fabsf(x));
    return fmaxf(x, 0.0f) + __logf(1.0f + t);
}

__device__ __forceinline__ short8 to_bf8(float4 u, float4 v) {
    short8 r;
    r[0] = bf16hw(u.x); r[1] = bf16hw(u.y); r[2] = bf16hw(u.z); r[3] = bf16hw(u.w);
    r[4] = bf16hw(v.x); r[5] = bf16hw(v.y); r[6] = bf16hw(v.z); r[7] = bf16hw(v.w);
    return r;
}

struct MlpW {
    short8 wb[2][2][4];   // [layer][ktile][ntile] B-frags, BN scale folded in
    float bias[2][4];     // fused linear-bias + BN shift (per lane's col)
    float wo[4];
    float bo;
};

__device__ __forceinline__ void load_weights(
    const float* __restrict__ W, const float* __restrict__ b,
    const float* __restrict__ g, const float* __restrict__ bt,
    const float* __restrict__ m, const float* __restrict__ v,
    const float* __restrict__ Wo, const float* __restrict__ bo, MlpW& w) {
    const int lane = threadIdx.x & 63;
    const int grp = lane >> 4, c = lane & 15;
#pragma unroll
    for (int l = 0; l < 2; ++l)
#pragma unroll
        for (int nt = 0; nt < 4; ++nt) {
            int j = nt * 16 + c;
            float s = g[l * 64 + j] * rsqrtf(v[l * 64 + j] + 1e-5f);
            w.bias[l][nt] = (b[l * 64 + j] - m[l * 64 + j]) * s + bt[l * 64 + j];
#pragma unroll
            for (int kt = 0; kt < 2; ++kt) {
                short8 f;
#pragma unroll
                for (int i = 0; i < 8; ++i)
                    f[i] = bf16hw(W[l * 4096 + (kt * 32 + grp * 8 + i) * 64 + j] * s);
                w.wb[l][kt][nt] = f;
            }
        }
#pragma unroll
    for (int nt = 0; nt < 4; ++nt) w.wo[nt] = Wo[nt * 16 + c];
    w.bo = bo[0];
}

// MLP on 16 rows (one wave). Lane's A-frag row = lane&15 at float offset row_off.
// out_s[r] = scalar for local row (lane>>4)*4 + r.
__device__ __forceinline__ void mlp_tile(const float* __restrict__ xbase, size_t row_off,
                                         const MlpW& w, unsigned short* lds, float out_s[4]) {
    const int lane = threadIdx.x & 63;
    const int grp = lane >> 4, c = lane & 15;
    const float4* rp = (const float4*)(xbase + row_off + grp * 8);
    float4 x0 = rp[0], x1 = rp[1], x2 = rp[8], x3 = rp[9];
    short8 a0 = to_bf8(x0, x1), a1 = to_bf8(x2, x3);
    f32x4 acc[4];
#pragma unroll
    for (int nt = 0; nt < 4; ++nt) {
        f32x4 z = {0.f, 0.f, 0.f, 0.f};
        z = __builtin_amdgcn_mfma_f32_16x16x32_bf16(a0, w.wb[0][0][nt], z, 0, 0, 0);
        z = __builtin_amdgcn_mfma_f32_16x16x32_bf16(a1, w.wb[0][1][nt], z, 0, 0, 0);
        acc[nt] = z;
    }
#pragma unroll
    for (int nt = 0; nt < 4; ++nt)
#pragma unroll
        for (int r = 0; r < 4; ++r) {
            float y = softplus_f(acc[nt][r] + w.bias[0][nt]);
            int row = grp * 4 + r;
            int byte = (row * 128 + (nt * 16 + c) * 2) ^ ((row & 7) << 4);
            *(unsigned short*)((char*)lds + byte) = (unsigned short)bf16hw(y);
        }
    asm volatile("s_waitcnt lgkmcnt(0)" ::: "memory");
    short8 b0 = *(const short8*)((char*)lds + ((c * 128 + grp * 16) ^ ((c & 7) << 4)));
    short8 b1 = *(const short8*)((char*)lds + ((c * 128 + 64 + grp * 16) ^ ((c & 7) << 4)));
    f32x4 acc2[4];
#pragma unroll
    for (int nt = 0; nt < 4; ++nt) {
        f32x4 z = {0.f, 0.f, 0.f, 0.f};
        z = __builtin_amdgcn_mfma_f32_16x16x32_bf16(b0, w.wb[1][0][nt], z, 0, 0, 0);
        z = __builtin_amdgcn_mfma_f32_16x16x32_bf16(b1, w.wb[1][1][nt], z, 0, 0, 0);
        acc2[nt] = z;
    }
    float p[4] = {0.f, 0.f, 0.f, 0.f};
#pragma unroll
    for (int nt = 0; nt < 4; ++nt)
#pragma unroll
        for (int r = 0; r < 4; ++r) {
            float y = softplus_f(acc2[nt][r] + w.bias[1][nt]);
            p[r] = fmaf(y, w.wo[nt], p[r]);
        }
#pragma unroll
    for (int msk = 1; msk < 16; msk <<= 1)
#pragma unroll
        for (int r = 0; r < 4; ++r) p[r] += __shfl_xor(p[r], msk);
#pragma unroll
    for (int r = 0; r < 4; ++r) out_s[r] = p[r] + w.bo;
}

// Dyad + scatter phase. sdata[el] = {dk.x,dk.y,dk.z, dj.x,dj.y,dj.z, s, tgt}
__device__ __forceinline__ void scatter_tile(const float (*sdata)[8], float* __restrict__ out) {
    const int lane = threadIdx.x & 63;
    asm volatile("s_waitcnt lgkmcnt(0)" ::: "memory");
#pragma unroll
    for (int p = 0; p < 3; ++p) {
        int idx = p * 64 + lane;
        if (idx < 144) {
            int el = idx / 9;
            int comp = idx - el * 9;
            int a = comp / 3, b2 = comp - a * 3;
            const float* sd = sdata[el];
            int tgt = __float_as_int(sd[7]);
            if (tgt >= 0) {
                float val = sd[6] * sd[a] * sd[3 + b2];
                atomicAdd(&out[tgt * 9 + comp], val);
            }
        }
    }
}

__global__ void geom_kernel(const float* __restrict__ pos,
                            const float* __restrict__ nbr_shift,
                            const int* __restrict__ edge_index,
                            float4* __restrict__ dirlen) {
    int e = blockIdx.x * blockDim.x + threadIdx.x;
    if (e >= NE) return;
    int j = edge_index[e];
    int i = edge_index[NE + e];
    float dx = __fsub_rn(__fadd_rn(pos[i * 3 + 0], nbr_shift[e * 3 + 0]), pos[j * 3 + 0]);
    float dy = __fsub_rn(__fadd_rn(pos[i * 3 + 1], nbr_shift[e * 3 + 1]), pos[j * 3 + 1]);
    float dz = __fsub_rn(__fadd_rn(pos[i * 3 + 2], nbr_shift[e * 3 + 2]), pos[j * 3 + 2]);
    float l2 = __fadd_rn(__fadd_rn(__fmul_rn(dx, dx), __fmul_rn(dy, dy)), __fmul_rn(dz, dz));
    float len = __fsqrt_rn(l2);
    float4 o;
    o.x = __fdiv_rn(dx, len);
    o.y = __fdiv_rn(dy, len);
    o.z = __fdiv_rn(dz, len);
    o.w = len;
    dirlen[e] = o;
}

__global__ __launch_bounds__(64) void compact_count(
    const int* __restrict__ idx_kj, const int* __restrict__ idx_ji,
    const float4* __restrict__ dirlen, int* __restrict__ waveCounts) {
    const int b = blockIdx.x;
    const int lane = threadIdx.x;
    const int base = b * ITEMS_PER_WAVE;
    int cnt = 0;
#pragma unroll 4
    for (int k = 0; k < ITEMS_PER_WAVE / 64; ++k) {
        int t = base + k * 64 + lane;
        bool pass = false;
        if (t < NT)
            pass = (dirlen[idx_kj[t]].w < CUT) && (dirlen[idx_ji[t]].w < CUT);
        cnt += __popcll(__ballot(pass));
    }
    if (lane == 0) waveCounts[b] = cnt;
}

__global__ __launch_bounds__(1024) void scan_kernel(const int* __restrict__ waveCounts,
                                                    int* __restrict__ waveOffsets,
                                                    int* __restrict__ counter) {
    __shared__ int s[1024];
    const int t = threadIdx.x;
    int c = (t < NWAVES) ? waveCounts[t] : 0;
    s[t] = c;
    __syncthreads();
#pragma unroll
    for (int off = 1; off < 1024; off <<= 1) {
        int v = (t >= off) ? s[t - off] : 0;
        __syncthreads();
        s[t] += v;
        __syncthreads();
    }
    if (t < NWAVES) waveOffsets[t] = s[t] - c;
    if (t == NWAVES - 1) *counter = s[t];
}

__global__ __launch_bounds__(64) void compact_write(
    const int* __restrict__ idx_kj, const int* __restrict__ idx_ji,
    const float4* __restrict__ dirlen, const int* __restrict__ waveOffsets,
    int* __restrict__ list) {
    const int b = blockIdx.x;
    const int lane = threadIdx.x;
    const int base = b * ITEMS_PER_WAVE;
    int run = waveOffsets[b];
    const unsigned long long lt = (1ull << lane) - 1ull;
#pragma unroll 4
    for (int k = 0; k < ITEMS_PER_WAVE / 64; ++k) {
        int t = base + k * 64 + lane;
        bool pass = false;
        if (t < NT)
            pass = (dirlen[idx_kj[t]].w < CUT) && (dirlen[idx_ji[t]].w < CUT);
        unsigned long long bal = __ballot(pass);
        if (pass) list[run + __popcll(bal & lt)] = t;
        run += __popcll(bal);
    }
}

__global__ __launch_bounds__(256) void edge_kernel(
    const float* __restrict__ edge_attr, const float* __restrict__ eW,
    const float* __restrict__ eb, const float* __restrict__ eg,
    const float* __restrict__ ebeta, const float* __restrict__ em,
    const float* __restrict__ ev, const float* __restrict__ eWo,
    const float* __restrict__ ebo, const int* __restrict__ edge_index,
    const float4* __restrict__ dirlen, float* __restrict__ out) {
    __shared__ __align__(16) unsigned short lds_t[4][1024];
    __shared__ __align__(16) float sdata[4][16][8];
    const int wave = threadIdx.x >> 6;
    const int lane = threadIdx.x & 63;
    MlpW w;
    load_weights(eW, eb, eg, ebeta, em, ev, eWo, ebo, w);
    const int gwave = blockIdx.x * 4 + wave;
    const int nwaves = gridDim.x * 4;
    const int ntiles = NE / 16;
    for (int tile = gwave; tile < ntiles; tile += nwaves) {
        float s[4];
        mlp_tile(edge_attr, (size_t)(tile * 16 + (lane & 15)) * 64, w, &lds_t[wave][0], s);
        if ((lane & 15) == 0) {
#pragma unroll
            for (int r = 0; r < 4; ++r) sdata[wave][(lane >> 4) * 4 + r][6] = s[r];
        }
        if (lane < 16) {
            int e = tile * 16 + lane;
            float4 d = dirlen[e];
            int tgt = edge_index[NE + e];
            float* sd = sdata[wave][lane];
            sd[0] = d.x; sd[1] = d.y; sd[2] = d.z;
            sd[3] = d.x; sd[4] = d.y; sd[5] = d.z;
            sd[7] = __int_as_float(tgt);
        }
        scatter_tile(sdata[wave], out);
    }
}

__global__ __launch_bounds__(256) void trip_kernel(
    const float* __restrict__ trip_attr, const float* __restrict__ tW,
    const float* __restrict__ tb, const float* __restrict__ tg,
    const float* __restrict__ tbeta, const float* __restrict__ tm,
    const float* __restrict__ tv, const float* __restrict__ tWo,
    const float* __restrict__ tbo, const int* __restrict__ idx_j,
    const int* __restrict__ idx_kj, const int* __restrict__ idx_ji,
    const float4* __restrict__ dirlen, const int* __restrict__ counter,
    const int* __restrict__ list, float* __restrict__ out) {
    __shared__ __align__(16) unsigned short lds_t[4][1024];
    __shared__ __align__(16) float sdata[4][16][8];
    const int wave = threadIdx.x >> 6;
    const int lane = threadIdx.x & 63;
    MlpW w;
    load_weights(tW, tb, tg, tbeta, tm, tv, tWo, tbo, w);
    const int cnt = *counter;
    const int gwave = blockIdx.x * 4 + wave;
    const int nwaves = gridDim.x * 4;
    const int ntiles = (cnt + 15) / 16;
    for (int tile = gwave; tile < ntiles; tile += nwaves) {
        int g = tile * 16 + (lane & 15);
        int trow = list[g < cnt ? g : 0];
        float s[4];
        mlp_tile(trip_attr, (size_t)trow * 64, w, &lds_t[wave][0], s);
        if ((lane & 15) == 0) {
#pragma unroll
            for (int r = 0; r < 4; ++r) sdata[wave][(lane >> 4) * 4 + r][6] = s[r];
        }
        if (lane < 16) {
            int gi = tile * 16 + lane;
            bool valid = gi < cnt;
            int t = list[valid ? gi : 0];
            int kj = idx_kj[t], ji = idx_ji[t];
            float4 dk = dirlen[kj];
            float4 dj = dirlen[ji];
            int tgt = valid ? idx_j[t] : -1;
            float* sd = sdata[wave][lane];
            sd[0] = dk.x; sd[1] = dk.y; sd[2] = dk.z;
            sd[3] = dj.x; sd[4] = dj.y; sd[5] = dj.z;
            sd[7] = __int_as_float(tgt);
        }
        scatter_tile(sdata[wave], out);
    }
}

extern "C" void kernel_launch(void* const* d_in, const int* in_sizes, int n_in,
                              void* d_out, int out_size, void* d_ws, size_t ws_size,
                              hipStream_t stream) {
    const float* pos       = (const float*)d_in[0];
    const float* nbr_shift = (const float*)d_in[1];
    const float* edge_attr = (const float*)d_in[2];
    const float* trip_attr = (const float*)d_in[3];
    const float* eW    = (const float*)d_in[4];
    const float* eb    = (const float*)d_in[5];
    const float* eg    = (const float*)d_in[6];
    const float* ebeta = (const float*)d_in[7];
    const float* em    = (const float*)d_in[8];
    const float* ev    = (const float*)d_in[9];
    const float* eWo   = (const float*)d_in[10];
    const float* ebo   = (const float*)d_in[11];
    const float* tW    = (const float*)d_in[12];
    const float* tb    = (const float*)d_in[13];
    const float* tg    = (const float*)d_in[14];
    const float* tbeta = (const float*)d_in[15];
    const float* tm    = (const float*)d_in[16];
    const float* tv    = (const float*)d_in[17];
    const float* tWo   = (const float*)d_in[18];
    const float* tbo   = (const float*)d_in[19];
    const int* edge_index = (const int*)d_in[20];
    const int* idx_j      = (const int*)d_in[21];
    const int* idx_kj     = (const int*)d_in[22];
    const int* idx_ji     = (const int*)d_in[23];
    float* out = (float*)d_out;

    char* ws = (char*)d_ws;
    float4* dirlen   = (float4*)ws;
    int* counter     = (int*)(ws + WS_CNT);
    int* waveCounts  = (int*)(ws + WS_WCNT);
    int* waveOffsets = (int*)(ws + WS_WOFF);
    int* list        = (int*)(ws + WS_LIST);

    hipMemsetAsync(d_out, 0, (size_t)out_size * sizeof(float), stream);
    geom_kernel<<<(NE + 255) / 256, 256, 0, stream>>>(pos, nbr_shift, edge_index, dirlen);
    compact_count<<<NWAVES, 64, 0, stream>>>(idx_kj, idx_ji, dirlen, waveCounts);
    scan_kernel<<<1, 1024, 0, stream>>>(waveCounts, waveOffsets, counter);
    compact_write<<<NWAVES, 64, 0, stream>>>(idx_kj, idx_ji, dirlen, waveOffsets, list);
    edge_kernel<<<1024, 256, 0, stream>>>(edge_attr, eW, eb, eg, ebeta, em, ev, eWo, ebo,
                                          edge_index, dirlen, out);
    trip_kernel<<<1024, 256, 0, stream>>>(trip_attr, tW, tb, tg, tbeta, tm, tv, tWo, tbo,
                                          idx_j, idx_kj, idx_ji, dirlen, counter, list, out);
}

// Round 4
// 229.255 us; speedup vs baseline: 2.5557x; 1.3884x over previous
//
#include <hip/hip_runtime.h>
#include <hip/hip_bf16.h>

#define NN 50000
#define NE 800000
#define NT 2000000
#define CUT 6.0f

// compaction geometry: one wave (64 lanes) handles 2048 triplets
#define ITEMS_PER_WAVE 2048
#define NWAVES ((NT + ITEMS_PER_WAVE - 1) / ITEMS_PER_WAVE)   // 977

// merged MLP kernel grid split
#define EDGE_BLOCKS 1792
#define TRIP_BLOCKS 832

// d_ws layout (bytes):
//   [0, 12,800,000)            float4 dirlen[NE]
//   [12,800,000, +800,000)     uchar  epass[NE]      (len < CUT)
//   [13,600,000, +64)          int    counter
//   [13,600,064, +4096)        int    waveCounts[NWAVES]
//   [13,604,160, +4096)        int    waveOffsets[NWAVES]
//   [13,608,256, +250,000)     u64    bitmask[NT/64]
//   [13,858,256, +8,000,000)   int    list[NT]
#define WS_EPASS  12800000
#define WS_CNT    13600000
#define WS_WCNT   13600064
#define WS_WOFF   13604160
#define WS_BMASK  13608256
#define WS_LIST   13858256

typedef __attribute__((ext_vector_type(8))) short short8;
typedef __attribute__((ext_vector_type(4))) float f32x4;

__device__ __forceinline__ short bf16_of(float f) {
    unsigned u = __float_as_uint(f);
    unsigned r = (u + 0x7fffu + ((u >> 16) & 1u)) >> 16;
    return (short)r;
}

__device__ __forceinline__ float softplus_f(float x) {
    float t = __expf(-fabsf(x));
    return fmaxf(x, 0.0f) + __logf(1.0f + t);
}

__device__ __forceinline__ short8 to_bf8(float4 u, float4 v) {
    short8 r;
    r[0] = bf16_of(u.x); r[1] = bf16_of(u.y); r[2] = bf16_of(u.z); r[3] = bf16_of(u.w);
    r[4] = bf16_of(v.x); r[5] = bf16_of(v.y); r[6] = bf16_of(v.z); r[7] = bf16_of(v.w);
    return r;
}

struct MlpW {
    short8 wb[2][2][4];   // [layer][ktile][ntile] B-frags, BN scale folded in
    float bias[2][4];     // fused linear-bias + BN shift (per lane's col)
    float wo[4];
    float bo;
};

struct PF {               // per-lane prefetch state for one 16-row tile
    float4 x0, x1, x2, x3;  // A-frag inputs (all lanes)
    float4 dv;              // lanes 0-15: d_kj ; lanes 16-31: d_ji
    int tgt;                // lanes 32-47: scatter target (-1 = skip)
};

__device__ __forceinline__ void load_weights(
    const float* __restrict__ W, const float* __restrict__ b,
    const float* __restrict__ g, const float* __restrict__ bt,
    const float* __restrict__ m, const float* __restrict__ v,
    const float* __restrict__ Wo, const float* __restrict__ bo, MlpW& w) {
    const int lane = threadIdx.x & 63;
    const int grp = lane >> 4, c = lane & 15;
#pragma unroll
    for (int l = 0; l < 2; ++l)
#pragma unroll
        for (int nt = 0; nt < 4; ++nt) {
            int j = nt * 16 + c;
            float s = g[l * 64 + j] * rsqrtf(v[l * 64 + j] + 1e-5f);
            w.bias[l][nt] = (b[l * 64 + j] - m[l * 64 + j]) * s + bt[l * 64 + j];
#pragma unroll
            for (int kt = 0; kt < 2; ++kt) {
                short8 f;
#pragma unroll
                for (int i = 0; i < 8; ++i)
                    f[i] = bf16_of(W[l * 4096 + (kt * 32 + grp * 8 + i) * 64 + j] * s);
                w.wb[l][kt][nt] = f;
            }
        }
#pragma unroll
    for (int nt = 0; nt < 4; ++nt) w.wo[nt] = Wo[nt * 16 + c];
    w.bo = bo[0];
}

__device__ __forceinline__ void pf_edge(int tile, const float* __restrict__ edge_attr,
                                        const float4* __restrict__ dirlen,
                                        const int* __restrict__ edge_index, PF& p) {
    const int lane = threadIdx.x & 63;
    const int grp = lane >> 4, c = lane & 15;
    const float4* rp = (const float4*)(edge_attr + (size_t)(tile * 16 + c) * 64 + grp * 8);
    p.x0 = rp[0]; p.x1 = rp[1]; p.x2 = rp[8]; p.x3 = rp[9];
    if (grp <= 1) {
        p.dv = dirlen[tile * 16 + c];
    } else if (grp == 2) {
        p.tgt = edge_index[NE + tile * 16 + c];
    }
}

__device__ __forceinline__ void pf_trip(int tile, int cnt, const float* __restrict__ trip_attr,
                                        const float4* __restrict__ dirlen,
                                        const int* __restrict__ idx_j,
                                        const int* __restrict__ idx_kj,
                                        const int* __restrict__ idx_ji,
                                        const int* __restrict__ list, PF& p) {
    const int lane = threadIdx.x & 63;
    const int grp = lane >> 4, c = lane & 15;
    int g = tile * 16 + c;
    bool valid = g < cnt;
    int trow = list[valid ? g : 0];
    const float4* rp = (const float4*)(trip_attr + (size_t)trow * 64 + grp * 8);
    p.x0 = rp[0]; p.x1 = rp[1]; p.x2 = rp[8]; p.x3 = rp[9];
    if (grp == 0) {
        p.dv = dirlen[idx_kj[trow]];
    } else if (grp == 1) {
        p.dv = dirlen[idx_ji[trow]];
    } else if (grp == 2) {
        p.tgt = valid ? idx_j[trow] : -1;
    }
}

// MLP + dyad scatter for one 16-row tile, inputs entirely from registers (PF).
__device__ __forceinline__ void tile_compute(const PF& p, const MlpW& w,
                                             unsigned short* lds, float (*sdata)[9],
                                             float* __restrict__ out) {
    const int lane = threadIdx.x & 63;
    const int grp = lane >> 4, c = lane & 15;
    short8 a0 = to_bf8(p.x0, p.x1), a1 = to_bf8(p.x2, p.x3);
    f32x4 acc[4];
#pragma unroll
    for (int nt = 0; nt < 4; ++nt) {
        f32x4 z = {0.f, 0.f, 0.f, 0.f};
        z = __builtin_amdgcn_mfma_f32_16x16x32_bf16(a0, w.wb[0][0][nt], z, 0, 0, 0);
        z = __builtin_amdgcn_mfma_f32_16x16x32_bf16(a1, w.wb[0][1][nt], z, 0, 0, 0);
        acc[nt] = z;
    }
#pragma unroll
    for (int nt = 0; nt < 4; ++nt)
#pragma unroll
        for (int r = 0; r < 4; ++r) {
            float y = softplus_f(acc[nt][r] + w.bias[0][nt]);
            int row = grp * 4 + r;
            int byte = (row * 128 + (nt * 16 + c) * 2) ^ ((row & 7) << 4);
            *(unsigned short*)((char*)lds + byte) = (unsigned short)bf16_of(y);
        }
    asm volatile("s_waitcnt lgkmcnt(0)" ::: "memory");
    short8 b0 = *(const short8*)((char*)lds + ((c * 128 + grp * 16) ^ ((c & 7) << 4)));
    short8 b1 = *(const short8*)((char*)lds + ((c * 128 + 64 + grp * 16) ^ ((c & 7) << 4)));
    f32x4 acc2[4];
#pragma unroll
    for (int nt = 0; nt < 4; ++nt) {
        f32x4 z = {0.f, 0.f, 0.f, 0.f};
        z = __builtin_amdgcn_mfma_f32_16x16x32_bf16(b0, w.wb[1][0][nt], z, 0, 0, 0);
        z = __builtin_amdgcn_mfma_f32_16x16x32_bf16(b1, w.wb[1][1][nt], z, 0, 0, 0);
        acc2[nt] = z;
    }
    float ps[4] = {0.f, 0.f, 0.f, 0.f};
#pragma unroll
    for (int nt = 0; nt < 4; ++nt)
#pragma unroll
        for (int r = 0; r < 4; ++r) {
            float y = softplus_f(acc2[nt][r] + w.bias[1][nt]);
            ps[r] = fmaf(y, w.wo[nt], ps[r]);
        }
#pragma unroll
    for (int msk = 1; msk < 16; msk <<= 1)
#pragma unroll
        for (int r = 0; r < 4; ++r) ps[r] += __shfl_xor(ps[r], msk);
    // stage scatter record: sdata[el] = {dk.xyz, dj.xyz, s, tgt} (width 9, pad)
    if (c == 0) {
#pragma unroll
        for (int r = 0; r < 4; ++r) sdata[grp * 4 + r][6] = ps[r] + w.bo;
    }
    if (grp == 0) {
        sdata[c][0] = p.dv.x; sdata[c][1] = p.dv.y; sdata[c][2] = p.dv.z;
    } else if (grp == 1) {
        sdata[c][3] = p.dv.x; sdata[c][4] = p.dv.y; sdata[c][5] = p.dv.z;
    } else if (grp == 2) {
        sdata[c][7] = __int_as_float(p.tgt);
    }
    asm volatile("s_waitcnt lgkmcnt(0)" ::: "memory");
#pragma unroll
    for (int ph = 0; ph < 3; ++ph) {
        int idx = ph * 64 + lane;
        if (idx < 144) {
            int el = idx / 9;
            int comp = idx - el * 9;
            int a = comp / 3, b2 = comp - a * 3;
            const float* sd = sdata[el];
            int tgt = __float_as_int(sd[7]);
            if (tgt >= 0) {
                float val = sd[6] * sd[a] * sd[3 + b2];
                atomicAdd(&out[tgt * 9 + comp], val);
            }
        }
    }
}

__global__ void geom_kernel(const float* __restrict__ pos,
                            const float* __restrict__ nbr_shift,
                            const int* __restrict__ edge_index,
                            float4* __restrict__ dirlen,
                            unsigned char* __restrict__ epass) {
    int e = blockIdx.x * blockDim.x + threadIdx.x;
    if (e >= NE) return;
    int j = edge_index[e];
    int i = edge_index[NE + e];
    float dx = __fsub_rn(__fadd_rn(pos[i * 3 + 0], nbr_shift[e * 3 + 0]), pos[j * 3 + 0]);
    float dy = __fsub_rn(__fadd_rn(pos[i * 3 + 1], nbr_shift[e * 3 + 1]), pos[j * 3 + 1]);
    float dz = __fsub_rn(__fadd_rn(pos[i * 3 + 2], nbr_shift[e * 3 + 2]), pos[j * 3 + 2]);
    float l2 = __fadd_rn(__fadd_rn(__fmul_rn(dx, dx), __fmul_rn(dy, dy)), __fmul_rn(dz, dz));
    float len = __fsqrt_rn(l2);
    float4 o;
    o.x = __fdiv_rn(dx, len);
    o.y = __fdiv_rn(dy, len);
    o.z = __fdiv_rn(dz, len);
    o.w = len;
    dirlen[e] = o;
    epass[e] = (len < CUT) ? 1 : 0;
}

__global__ __launch_bounds__(64) void compact_count(
    const int* __restrict__ idx_kj, const int* __restrict__ idx_ji,
    const unsigned char* __restrict__ epass, int* __restrict__ waveCounts,
    unsigned long long* __restrict__ bitmask) {
    const int b = blockIdx.x;
    const int lane = threadIdx.x;
    const int base = b * ITEMS_PER_WAVE;
    int cnt = 0;
#pragma unroll 4
    for (int k = 0; k < ITEMS_PER_WAVE / 64; ++k) {
        int t = base + k * 64 + lane;
        bool pass = false;
        if (t < NT)
            pass = (epass[idx_kj[t]] & epass[idx_ji[t]]) != 0;
        unsigned long long bal = __ballot(pass);
        if (lane == 0) bitmask[b * 32 + k] = bal;
        cnt += __popcll(bal);
    }
    if (lane == 0) waveCounts[b] = cnt;
}

__global__ __launch_bounds__(1024) void scan_kernel(const int* __restrict__ waveCounts,
                                                    int* __restrict__ waveOffsets,
                                                    int* __restrict__ counter) {
    __shared__ int s[1024];
    const int t = threadIdx.x;
    int c = (t < NWAVES) ? waveCounts[t] : 0;
    s[t] = c;
    __syncthreads();
#pragma unroll
    for (int off = 1; off < 1024; off <<= 1) {
        int v = (t >= off) ? s[t - off] : 0;
        __syncthreads();
        s[t] += v;
        __syncthreads();
    }
    if (t < NWAVES) waveOffsets[t] = s[t] - c;
    if (t == NWAVES - 1) *counter = s[t];
}

__global__ __launch_bounds__(64) void compact_write(
    const unsigned long long* __restrict__ bitmask, const int* __restrict__ waveOffsets,
    int* __restrict__ list) {
    const int b = blockIdx.x;
    const int lane = threadIdx.x;
    const int base = b * ITEMS_PER_WAVE;
    int run = waveOffsets[b];
    const unsigned long long lt = (1ull << lane) - 1ull;
#pragma unroll 4
    for (int k = 0; k < ITEMS_PER_WAVE / 64; ++k) {
        unsigned long long bal = bitmask[b * 32 + k];
        if ((bal >> lane) & 1ull)
            list[run + __popcll(bal & lt)] = base + k * 64 + lane;
        run += __popcll(bal);
    }
}

__global__ __launch_bounds__(256) void mlp_kernel(
    const float* __restrict__ edge_attr, const float* __restrict__ trip_attr,
    const float* __restrict__ eW, const float* __restrict__ eb,
    const float* __restrict__ eg, const float* __restrict__ ebeta,
    const float* __restrict__ em, const float* __restrict__ ev,
    const float* __restrict__ eWo, const float* __restrict__ ebo,
    const float* __restrict__ tW, const float* __restrict__ tb,
    const float* __restrict__ tg, const float* __restrict__ tbeta,
    const float* __restrict__ tm, const float* __restrict__ tv,
    const float* __restrict__ tWo, const float* __restrict__ tbo,
    const int* __restrict__ edge_index, const int* __restrict__ idx_j,
    const int* __restrict__ idx_kj, const int* __restrict__ idx_ji,
    const float4* __restrict__ dirlen, const int* __restrict__ counter,
    const int* __restrict__ list, float* __restrict__ out) {
    __shared__ __align__(16) unsigned short lds_t[4][1024];
    __shared__ __align__(16) float sdata[4][16][9];
    const int wave = threadIdx.x >> 6;
    unsigned short* lds = &lds_t[wave][0];
    float (*sd)[9] = sdata[wave];
    MlpW w;
    PF cur, nxt;
    if (blockIdx.x < EDGE_BLOCKS) {
        load_weights(eW, eb, eg, ebeta, em, ev, eWo, ebo, w);
        const int gwave = blockIdx.x * 4 + wave;
        const int stride = EDGE_BLOCKS * 4;
        const int ntiles = NE / 16;
        int tile = gwave;
        if (tile < ntiles) pf_edge(tile, edge_attr, dirlen, edge_index, cur);
        for (; tile < ntiles; tile += stride) {
            int tn = tile + stride;
            if (tn < ntiles) pf_edge(tn, edge_attr, dirlen, edge_index, nxt);
            tile_compute(cur, w, lds, sd, out);
            cur = nxt;
        }
    } else {
        load_weights(tW, tb, tg, tbeta, tm, tv, tWo, tbo, w);
        const int cnt = *counter;
        const int gwave = (blockIdx.x - EDGE_BLOCKS) * 4 + wave;
        const int stride = TRIP_BLOCKS * 4;
        const int ntiles = (cnt + 15) / 16;
        int tile = gwave;
        if (tile < ntiles) pf_trip(tile, cnt, trip_attr, dirlen, idx_j, idx_kj, idx_ji, list, cur);
        for (; tile < ntiles; tile += stride) {
            int tn = tile + stride;
            if (tn < ntiles) pf_trip(tn, cnt, trip_attr, dirlen, idx_j, idx_kj, idx_ji, list, nxt);
            tile_compute(cur, w, lds, sd, out);
            cur = nxt;
        }
    }
}

extern "C" void kernel_launch(void* const* d_in, const int* in_sizes, int n_in,
                              void* d_out, int out_size, void* d_ws, size_t ws_size,
                              hipStream_t stream) {
    const float* pos       = (const float*)d_in[0];
    const float* nbr_shift = (const float*)d_in[1];
    const float* edge_attr = (const float*)d_in[2];
    const float* trip_attr = (const float*)d_in[3];
    const float* eW    = (const float*)d_in[4];
    const float* eb    = (const float*)d_in[5];
    const float* eg    = (const float*)d_in[6];
    const float* ebeta = (const float*)d_in[7];
    const float* em    = (const float*)d_in[8];
    const float* ev    = (const float*)d_in[9];
    const float* eWo   = (const float*)d_in[10];
    const float* ebo   = (const float*)d_in[11];
    const float* tW    = (const float*)d_in[12];
    const float* tb    = (const float*)d_in[13];
    const float* tg    = (const float*)d_in[14];
    const float* tbeta = (const float*)d_in[15];
    const float* tm    = (const float*)d_in[16];
    const float* tv    = (const float*)d_in[17];
    const float* tWo   = (const float*)d_in[18];
    const float* tbo   = (const float*)d_in[19];
    const int* edge_index = (const int*)d_in[20];
    const int* idx_j      = (const int*)d_in[21];
    const int* idx_kj     = (const int*)d_in[22];
    const int* idx_ji     = (const int*)d_in[23];
    float* out = (float*)d_out;

    char* ws = (char*)d_ws;
    float4* dirlen        = (float4*)ws;
    unsigned char* epass  = (unsigned char*)(ws + WS_EPASS);
    int* counter          = (int*)(ws + WS_CNT);
    int* waveCounts       = (int*)(ws + WS_WCNT);
    int* waveOffsets      = (int*)(ws + WS_WOFF);
    unsigned long long* bm = (unsigned long long*)(ws + WS_BMASK);
    int* list             = (int*)(ws + WS_LIST);

    hipMemsetAsync(d_out, 0, (size_t)out_size * sizeof(float), stream);
    geom_kernel<<<(NE + 255) / 256, 256, 0, stream>>>(pos, nbr_shift, edge_index, dirlen, epass);
    compact_count<<<NWAVES, 64, 0, stream>>>(idx_kj, idx_ji, epass, waveCounts, bm);
    scan_kernel<<<1, 1024, 0, stream>>>(waveCounts, waveOffsets, counter);
    compact_write<<<NWAVES, 64, 0, stream>>>(bm, waveOffsets, list);
    mlp_kernel<<<EDGE_BLOCKS + TRIP_BLOCKS, 256, 0, stream>>>(
        edge_attr, trip_attr,
        eW, eb, eg, ebeta, em, ev, eWo, ebo,
        tW, tb, tg, tbeta, tm, tv, tWo, tbo,
        edge_index, idx_j, idx_kj, idx_ji,
        dirlen, counter, list, out);
}